// Round 21
// baseline (190.049 us; speedup 1.0000x reference)
//
#include <hip/hip_runtime.h>

// GCN autoencoder: recon = (Z @ Z^T).
// R21 = R20 (best, 189.1us) + front re-order. Scatter depends only on
// cursor==0, NOT on gemm -> K0: zero cursor alone (tiny); K1': gemm and
// scatter FUSED split-grid (run concurrently); K3: spmm1_mlp; K4: spmm2;
// K5: zzt (R20 body: 64x256, nt stores, XCD-chunked swizzle - ledger:
// nt +12, tile +22, swizzle +5; all other zzt variants <=0).
// Serial path: K0(3)+K1'(17)+K3+K4+zzt vs K1(17)+K2(8)+... -> ~5-8us less.

constexpr int N_   = 10000;
constexpr int E_   = 320000;
constexpr int F_   = 512;
constexpr int H1_  = 32;
constexpr int H2_  = 16;
constexpr int CAP_ = 96;   // ELL row capacity; P[Poisson(32) > 96] ~ 3e-20

typedef float f32x4 __attribute__((ext_vector_type(4)));

// ---------------- K0: zero cursor ----------------
__global__ __launch_bounds__(256) void zero_cursor(int* __restrict__ cursor) {
    int i = blockIdx.x * blockDim.x + threadIdx.x;
    if (i < N_) cursor[i] = 0;
}

// ---------------- K1': gemm (h = X @ W1) || scatter-ELL, split grid --------
constexpr int GEMM_THREADS  = N_ * (H1_ / 4);             // 80000
constexpr int GEMM_BLOCKS   = (GEMM_THREADS + 255) / 256; // 313
constexpr int SCAT_BLOCKS   = (E_ + 255) / 256;           // 1250

__global__ __launch_bounds__(256) void gemm_scatter(const float* __restrict__ x,
                                                    const float* __restrict__ W1,
                                                    float* __restrict__ h,
                                                    const int* __restrict__ erow,
                                                    const int* __restrict__ ecol,
                                                    const float* __restrict__ ew,
                                                    int* __restrict__ cursor,
                                                    int* __restrict__ cole,
                                                    float* __restrict__ we) {
    if (blockIdx.x >= GEMM_BLOCKS) {
        // scatter part (cursor zeroed by K0)
        int e = (blockIdx.x - GEMM_BLOCKS) * 256 + threadIdx.x;
        if (e >= E_) return;
        int r = erow[e];
        int p = atomicAdd(&cursor[r], 1);
        if (p < CAP_) {                   // overflow-impossible guard
            size_t idx = (size_t)r * CAP_ + p;
            cole[idx] = ecol[e];
            we[idx]   = ew[e];
        }
        return;
    }
    int tid = blockIdx.x * blockDim.x + threadIdx.x;
    if (tid >= GEMM_THREADS) return;
    int r  = tid >> 3;              // /8
    int cq = (tid & 7) * 4;         // column quad 0,4,...,28
    const float4* xr = reinterpret_cast<const float4*>(x + (size_t)r * F_);
    float4 acc = make_float4(0.f, 0.f, 0.f, 0.f);
#pragma unroll 4
    for (int k4 = 0; k4 < F_ / 4; ++k4) {
        float4 xv = xr[k4];
        int k = k4 * 4;
        float4 w0 = *reinterpret_cast<const float4*>(W1 + (k + 0) * H1_ + cq);
        float4 w1 = *reinterpret_cast<const float4*>(W1 + (k + 1) * H1_ + cq);
        float4 w2 = *reinterpret_cast<const float4*>(W1 + (k + 2) * H1_ + cq);
        float4 w3 = *reinterpret_cast<const float4*>(W1 + (k + 3) * H1_ + cq);
        acc.x = fmaf(xv.x, w0.x, acc.x); acc.y = fmaf(xv.x, w0.y, acc.y);
        acc.z = fmaf(xv.x, w0.z, acc.z); acc.w = fmaf(xv.x, w0.w, acc.w);
        acc.x = fmaf(xv.y, w1.x, acc.x); acc.y = fmaf(xv.y, w1.y, acc.y);
        acc.z = fmaf(xv.y, w1.z, acc.z); acc.w = fmaf(xv.y, w1.w, acc.w);
        acc.x = fmaf(xv.z, w2.x, acc.x); acc.y = fmaf(xv.z, w2.y, acc.y);
        acc.z = fmaf(xv.z, w2.z, acc.z); acc.w = fmaf(xv.z, w2.w, acc.w);
        acc.x = fmaf(xv.w, w3.x, acc.x); acc.y = fmaf(xv.w, w3.y, acc.y);
        acc.z = fmaf(xv.w, w3.z, acc.z); acc.w = fmaf(xv.w, w3.w, acc.w);
    }
    *reinterpret_cast<float4*>(h + (size_t)r * H1_ + cq) = acc;
}

// ---------------- K3: h2 = relu(A @ h) @ W2  (8 rows / block) --------------
__global__ __launch_bounds__(256) void spmm1_mlp(const float* __restrict__ h,
                                                 const int* __restrict__ cursor,
                                                 const int* __restrict__ cole,
                                                 const float* __restrict__ we,
                                                 const float* __restrict__ W2,
                                                 float* __restrict__ h2) {
    __shared__ float sh1[8][H1_ + 1];
    __shared__ float sW2[H1_ * H2_];
    const int t = threadIdx.x;
    sW2[t]       = W2[t];
    sW2[t + 256] = W2[t + 256];

    const int rl = t >> 5;           // 0..7
    const int f  = t & (H1_ - 1);
    const int r  = blockIdx.x * 8 + rl;
    float acc = 0.f;
    if (r < N_) {
        const int deg = cursor[r];
        const int*   cp = cole + (size_t)r * CAP_;   // 384B-aligned
        const float* wp = we   + (size_t)r * CAP_;
        int p = 0;
        for (; p + 8 <= deg; p += 8) {
            int4   c0 = *reinterpret_cast<const int4*>(cp + p);
            int4   c1 = *reinterpret_cast<const int4*>(cp + p + 4);
            float4 w0 = *reinterpret_cast<const float4*>(wp + p);
            float4 w1 = *reinterpret_cast<const float4*>(wp + p + 4);
            float g0 = h[(size_t)c0.x * H1_ + f];
            float g1 = h[(size_t)c0.y * H1_ + f];
            float g2 = h[(size_t)c0.z * H1_ + f];
            float g3 = h[(size_t)c0.w * H1_ + f];
            float g4 = h[(size_t)c1.x * H1_ + f];
            float g5 = h[(size_t)c1.y * H1_ + f];
            float g6 = h[(size_t)c1.z * H1_ + f];
            float g7 = h[(size_t)c1.w * H1_ + f];
            acc = fmaf(w0.x, g0, acc);
            acc = fmaf(w0.y, g1, acc);
            acc = fmaf(w0.z, g2, acc);
            acc = fmaf(w0.w, g3, acc);
            acc = fmaf(w1.x, g4, acc);
            acc = fmaf(w1.y, g5, acc);
            acc = fmaf(w1.z, g6, acc);
            acc = fmaf(w1.w, g7, acc);
        }
        for (; p < deg; ++p)
            acc = fmaf(wp[p], h[(size_t)cp[p] * H1_ + f], acc);
    }
    sh1[rl][f] = fmaxf(acc, 0.f);     // relu fused here
    __syncthreads();

    if (t < 128) {
        const int r2l = t >> 4;       // 0..7
        const int c   = t & (H2_ - 1);
        const int r2  = blockIdx.x * 8 + r2l;
        if (r2 < N_) {
            float a = 0.f;
#pragma unroll
            for (int k = 0; k < H1_; ++k)
                a = fmaf(sh1[r2l][k], sW2[k * H2_ + c], a);
            h2[(size_t)r2 * H2_ + c] = a;
        }
    }
}

// ---------------- K4: z = A @ h2  (16 rows / block) ----------------
__global__ __launch_bounds__(256) void spmm2(const float* __restrict__ h2,
                                             const int* __restrict__ cursor,
                                             const int* __restrict__ cole,
                                             const float* __restrict__ we,
                                             float* __restrict__ z) {
    const int t = threadIdx.x;
    const int rl = t >> 4;            // 0..15
    const int f  = t & (H2_ - 1);
    const int r  = blockIdx.x * 16 + rl;
    if (r >= N_) return;
    const int deg = cursor[r];
    const int*   cp = cole + (size_t)r * CAP_;
    const float* wp = we   + (size_t)r * CAP_;
    float acc = 0.f;
    int p = 0;
    for (; p + 8 <= deg; p += 8) {
        int4   c0 = *reinterpret_cast<const int4*>(cp + p);
        int4   c1 = *reinterpret_cast<const int4*>(cp + p + 4);
        float4 w0 = *reinterpret_cast<const float4*>(wp + p);
        float4 w1 = *reinterpret_cast<const float4*>(wp + p + 4);
        float g0 = h2[(size_t)c0.x * H2_ + f];
        float g1 = h2[(size_t)c0.y * H2_ + f];
        float g2 = h2[(size_t)c0.z * H2_ + f];
        float g3 = h2[(size_t)c0.w * H2_ + f];
        float g4 = h2[(size_t)c1.x * H2_ + f];
        float g5 = h2[(size_t)c1.y * H2_ + f];
        float g6 = h2[(size_t)c1.z * H2_ + f];
        float g7 = h2[(size_t)c1.w * H2_ + f];
        acc = fmaf(w0.x, g0, acc);
        acc = fmaf(w0.y, g1, acc);
        acc = fmaf(w0.z, g2, acc);
        acc = fmaf(w0.w, g3, acc);
        acc = fmaf(w1.x, g4, acc);
        acc = fmaf(w1.y, g5, acc);
        acc = fmaf(w1.z, g6, acc);
        acc = fmaf(w1.w, g7, acc);
    }
    for (; p < deg; ++p)
        acc = fmaf(wp[p], h2[(size_t)cp[p] * H2_ + f], acc);
    z[(size_t)r * H2_ + f] = acc;
}

// ---------------- K5: out = z @ z^T  (R20: 64x256, nt, XCD swizzle) --------
constexpr int BI = 64;
constexpr int BJ = 256;
constexpr int NBX = (N_ + BJ - 1) / BJ;      // 40
constexpr int NBY = (N_ + BI - 1) / BI;      // 157
constexpr int NBLK = NBX * NBY;              // 6280; % 8 == 0 -> bijective
constexpr int CHUNK = NBLK / 8;              // 785

__global__ __launch_bounds__(256) void zzt(const float* __restrict__ z,
                                           float* __restrict__ out) {
    __shared__ float zi[H2_][BI + 4];    // 16 x 68
    __shared__ float zj[H2_][BJ + 8];    // 16 x 264
    const int t = threadIdx.x;

    const int lin = blockIdx.y * NBX + blockIdx.x;       // hw dispatch order
    const int v   = (lin & 7) * CHUNK + (lin >> 3);      // XCD-chunked, bijective
    const int by  = v / NBX;
    const int bx  = v % NBX;
    const int ib  = by * BI;
    const int jb  = bx * BJ;

    {
        int row = t >> 2;
        int kq  = (t & 3) * 4;
        int gr  = ib + row;
        float4 val = (gr < N_)
            ? *reinterpret_cast<const float4*>(z + (size_t)gr * H2_ + kq)
            : make_float4(0.f, 0.f, 0.f, 0.f);
        zi[kq + 0][row] = val.x;
        zi[kq + 1][row] = val.y;
        zi[kq + 2][row] = val.z;
        zi[kq + 3][row] = val.w;
    }
#pragma unroll
    for (int it = 0; it < 4; ++it) {
        int idx = it * 256 + t;
        int row = idx >> 2;
        int kq  = (idx & 3) * 4;
        int gr  = jb + row;
        float4 val = (gr < N_)
            ? *reinterpret_cast<const float4*>(z + (size_t)gr * H2_ + kq)
            : make_float4(0.f, 0.f, 0.f, 0.f);
        zj[kq + 0][row] = val.x;
        zj[kq + 1][row] = val.y;
        zj[kq + 2][row] = val.z;
        zj[kq + 3][row] = val.w;
    }
    __syncthreads();

    const int tj = t & 31;          // 32 j-lanes
    const int i0 = (t >> 5) * 8;    // 8 i-groups of 8 rows

    float4 accA[8] = {};            // j = jb + tj*4 .. +3
    float4 accB[8] = {};            // j = jb + 128 + tj*4 .. +3

#pragma unroll
    for (int k = 0; k < H2_; ++k) {
        float4 b0 = *reinterpret_cast<const float4*>(&zj[k][tj * 4]);
        float4 b1 = *reinterpret_cast<const float4*>(&zj[k][128 + tj * 4]);
        float4 a0 = *reinterpret_cast<const float4*>(&zi[k][i0]);      // bcast
        float4 a1 = *reinterpret_cast<const float4*>(&zi[k][i0 + 4]);  // bcast
        float av[8] = {a0.x, a0.y, a0.z, a0.w, a1.x, a1.y, a1.z, a1.w};
#pragma unroll
        for (int ii = 0; ii < 8; ++ii) {
            accA[ii].x = fmaf(av[ii], b0.x, accA[ii].x);
            accA[ii].y = fmaf(av[ii], b0.y, accA[ii].y);
            accA[ii].z = fmaf(av[ii], b0.z, accA[ii].z);
            accA[ii].w = fmaf(av[ii], b0.w, accA[ii].w);
            accB[ii].x = fmaf(av[ii], b1.x, accB[ii].x);
            accB[ii].y = fmaf(av[ii], b1.y, accB[ii].y);
            accB[ii].z = fmaf(av[ii], b1.z, accB[ii].z);
            accB[ii].w = fmaf(av[ii], b1.w, accB[ii].w);
        }
    }

    const int j0 = jb + tj * 4;
    const int j1 = jb + 128 + tj * 4;
#pragma unroll
    for (int ii = 0; ii < 8; ++ii) {
        int gi = ib + i0 + ii;
        if (gi >= N_) break;
        float* orow = out + (size_t)gi * N_;
        if (j0 + 3 < N_) {
            f32x4 val = {accA[ii].x, accA[ii].y, accA[ii].z, accA[ii].w};
            __builtin_nontemporal_store(val, reinterpret_cast<f32x4*>(orow + j0));
        } else {
            float a[4] = {accA[ii].x, accA[ii].y, accA[ii].z, accA[ii].w};
            for (int jj = 0; jj < 4; ++jj)
                if (j0 + jj < N_) orow[j0 + jj] = a[jj];
        }
        if (j1 + 3 < N_) {
            f32x4 val = {accB[ii].x, accB[ii].y, accB[ii].z, accB[ii].w};
            __builtin_nontemporal_store(val, reinterpret_cast<f32x4*>(orow + j1));
        } else {
            float b[4] = {accB[ii].x, accB[ii].y, accB[ii].z, accB[ii].w};
            for (int jj = 0; jj < 4; ++jj)
                if (j1 + jj < N_) orow[j1 + jj] = b[jj];
        }
    }
}

extern "C" void kernel_launch(void* const* d_in, const int* in_sizes, int n_in,
                              void* d_out, int out_size, void* d_ws, size_t ws_size,
                              hipStream_t stream) {
    const float* x    = (const float*)d_in[0];
    const float* ew   = (const float*)d_in[1];
    const float* W1   = (const float*)d_in[2];
    const float* W2   = (const float*)d_in[3];
    const int*   erow = (const int*)d_in[4];
    const int*   ecol = (const int*)d_in[5];
    float* out = (float*)d_out;

    // workspace layout (4B elements) — same as R13/R20
    float* h      = (float*)d_ws;              // N*H1
    float* h2     = h  + (size_t)N_ * H1_;     // N*H2
    float* z      = h2 + (size_t)N_ * H2_;     // N*H2
    float* we     = z  + (size_t)N_ * H2_;     // N*CAP
    int*   cole   = (int*)(we + (size_t)N_ * CAP_);   // N*CAP
    int*   cursor = cole + (size_t)N_ * CAP_;  // N

    zero_cursor<<<(N_ + 255) / 256, 256, 0, stream>>>(cursor);
    gemm_scatter<<<GEMM_BLOCKS + SCAT_BLOCKS, 256, 0, stream>>>(
        x, W1, h, erow, ecol, ew, cursor, cole, we);
    spmm1_mlp<<<(N_ + 7) / 8, 256, 0, stream>>>(h, cursor, cole, we, W2, h2);
    spmm2<<<(N_ + 15) / 16, 256, 0, stream>>>(h2, cursor, cole, we, z);

    dim3 grid(NBX, NBY);   // 40 x 157
    zzt<<<grid, 256, 0, stream>>>(z, out);
}